// Round 12
// baseline (121.433 us; speedup 1.0000x reference)
//
#include <hip/hip_runtime.h>
#include <math.h>

#define NB 1024   // batch
#define NC 64     // input dim
#define NH 128    // hidden dim
#define MAX_IT 500
#define TOLF 1e-3f

typedef _Float16 f16x8 __attribute__((ext_vector_type(8)));
typedef float    f32x4 __attribute__((ext_vector_type(4)));
typedef _Float16 h2    __attribute__((ext_vector_type(2)));

#define MFMA(a, b, c) __builtin_amdgcn_mfma_f32_16x16x32_f16((a), (b), (c), 0, 0, 0)

__device__ __forceinline__ unsigned pack_h2(float a, float b) {
    union { h2 h; unsigned u; } cv;
    cv.h.x = (_Float16)a; cv.h.y = (_Float16)b; return cv.u;
}
__device__ __forceinline__ float rcp_fast(float x) {
#if __has_builtin(__builtin_amdgcn_rcpf)
    return __builtin_amdgcn_rcpf(x);
#else
    return 1.0f / x;
#endif
}
__device__ __forceinline__ void sigsp(float a, float& sig, float& sp) {
    const float e = __expf(-fabsf(a));
    const float r = rcp_fast(1.0f + e);
    sig = (a >= 0.0f) ? r : e * r;
    sp  = fmaxf(a, 0.0f) + __logf(1.0f + e);
}
__device__ __forceinline__ float sigm(float a) {
    const float e = __expf(-fabsf(a));
    const float r = rcp_fast(1.0f + e);
    return (a >= 0.0f) ? r : e * r;
}
__device__ __forceinline__ float clp(float x) { return fmaxf(x, 0.0f); }

// R12: latency model (R9-R11 evidence): T = iters x phases x L, L~390 cyc
// dominated by dep-chains + barrier, NOT LDS issue (R10/R11 flat proved it).
// (a) 6 -> 4 barriers: defer sg2 (v1 stored WITHOUT the head sigmoid; folded
//     in later since all consumers are linear), and make the final adjoint
//     per-sample-per-wave so the residual norm is intra-wave.
// (b) heavy-ball momentum on the Richardson update (sqrt(kappa) iters).
__launch_bounds__(256, 1)
__global__ void blnn_kernel(const float* __restrict__ xin,
                            const float* __restrict__ Wy0,
                            const float* __restrict__ by0,
                            const float* __restrict__ Wy1,
                            const float* __restrict__ by1,
                            const float* __restrict__ Wz1,
                            const float* __restrict__ Wy2,
                            const float* __restrict__ by2,
                            const float* __restrict__ Wz2,
                            float* __restrict__ out)
{
    // A-frag weight tiles (identical staging to R9): [tile][lane] uint4.
    __shared__ uint4 WA0q[16 * 64];   // Wy0   (M=128,K=64):  mt8 x ks2
    __shared__ uint4 WA1q[16 * 64];   // Wy1
    __shared__ uint4 WAZq[32 * 64];   // Wz1+  (M=128,K=128): mt8 x ks4
    __shared__ uint4 WZTq[32 * 64];   // Wz1+^T
    __shared__ uint4 W1Tq[16 * 64];   // Wy1^T (M=64,K=128):  mt4 x ks4
    __shared__ uint4 W0Tq[16 * 64];   // Wy0^T
    __shared__ __align__(16) _Float16 xact [4 * 72];   // x  per sample
    __shared__ __align__(16) _Float16 h0act[4 * 136];  // h0 per sample
    __shared__ __align__(16) _Float16 v1act[4 * 136];  // ~v1 (no sg2!)
    __shared__ __align__(16) _Float16 v0act[4 * 136];
    __shared__ __align__(16) float by0f[128], by1f[128], wz2f[128];
    __shared__ __align__(16) float hp[16];    // head partials [n4][w]
    __shared__ __align__(16) float pxp[4];    // wy2.x per sample
    __shared__ __align__(16) float norms[4];  // per-sample n^2 (0 if frozen)

    const int tid  = threadIdx.x;
    const int w    = tid >> 6;
    const int l    = tid & 63;
    const int n    = l & 15;          // MFMA col
    const int n4   = n & 3;           // real sample (col role)
    const int quad = l >> 4;
    const int blk4 = blockIdx.x * 4;

    // ---- stage weights into A-frag order (same as R9) ----
    for (int f = tid; f < 16 * 64; f += 256) {        // WA0 / WA1
        const int tile = f >> 6, q = f & 63;
        const int mt = tile >> 1, ks = tile & 1;
        const int row = mt * 16 + (q & 15);
        const int k0  = ks * 32 + ((q >> 4) << 3);
        const float* p0 = Wy0 + row * 64 + k0;
        WA0q[f] = make_uint4(pack_h2(p0[0], p0[1]), pack_h2(p0[2], p0[3]),
                             pack_h2(p0[4], p0[5]), pack_h2(p0[6], p0[7]));
        const float* p1 = Wy1 + row * 64 + k0;
        WA1q[f] = make_uint4(pack_h2(p1[0], p1[1]), pack_h2(p1[2], p1[3]),
                             pack_h2(p1[4], p1[5]), pack_h2(p1[6], p1[7]));
    }
    for (int f = tid; f < 32 * 64; f += 256) {        // WAZ / WZT (clip >= 0)
        const int tile = f >> 6, q = f & 63;
        const int mt = tile >> 2, ks = tile & 3;
        const int row = mt * 16 + (q & 15);
        const int k0  = ks * 32 + ((q >> 4) << 3);
        const float* p = Wz1 + row * 128 + k0;
        WAZq[f] = make_uint4(pack_h2(clp(p[0]), clp(p[1])), pack_h2(clp(p[2]), clp(p[3])),
                             pack_h2(clp(p[4]), clp(p[5])), pack_h2(clp(p[6]), clp(p[7])));
        const float* pt = Wz1 + k0 * 128 + row;
        WZTq[f] = make_uint4(pack_h2(clp(pt[0]),   clp(pt[128])),
                             pack_h2(clp(pt[256]), clp(pt[384])),
                             pack_h2(clp(pt[512]), clp(pt[640])),
                             pack_h2(clp(pt[768]), clp(pt[896])));
    }
    for (int f = tid; f < 16 * 64; f += 256) {        // W1T / W0T
        const int tile = f >> 6, q = f & 63;
        const int mt = tile >> 2, ks = tile & 3;
        const int rowT = mt * 16 + (q & 15);
        const int k0   = ks * 32 + ((q >> 4) << 3);
        const float* p1 = Wy1 + k0 * 64 + rowT;
        W1Tq[f] = make_uint4(pack_h2(p1[0],   p1[64]),  pack_h2(p1[128], p1[192]),
                             pack_h2(p1[256], p1[320]), pack_h2(p1[384], p1[448]));
        const float* p0 = Wy0 + k0 * 64 + rowT;
        W0Tq[f] = make_uint4(pack_h2(p0[0],   p0[64]),  pack_h2(p0[128], p0[192]),
                             pack_h2(p0[256], p0[320]), pack_h2(p0[384], p0[448]));
    }
    if (tid < 128) {
        by0f[tid] = by0[tid];
        by1f[tid] = by1[tid];
        wz2f[tid] = fmaxf(Wz2[tid], 0.0f);
    }
    {   // x0 = z into act layout
        const int nn = tid >> 6, cc = tid & 63;
        xact[nn * 72 + cc] = (_Float16)xin[(blk4 + nn) * 64 + cc];
    }

    // ---- per-wave sample-role state: wave w owns sample w, all 64 comps.
    // lane comps: c = mt*16 + quad*4 + r, mt=0..3, r=0..3 (n-lanes duplicate).
    float zr[16], wy2r[16], xc[16], xp[16];
    {
        const float4* xin4 = (const float4*)xin;
        const float4* wy24 = (const float4*)Wy2;
        #pragma unroll
        for (int mt = 0; mt < 4; ++mt) {
            const float4 zt = xin4[(blk4 + w) * 16 + mt * 4 + quad];
            const float4 wt = wy24[mt * 4 + quad];
            zr[mt*4+0] = zt.x; zr[mt*4+1] = zt.y; zr[mt*4+2] = zt.z; zr[mt*4+3] = zt.w;
            wy2r[mt*4+0] = wt.x; wy2r[mt*4+1] = wt.y; wy2r[mt*4+2] = wt.z; wy2r[mt*4+3] = wt.w;
        }
        #pragma unroll
        for (int i = 0; i < 16; ++i) { xc[i] = zr[i]; xp[i] = zr[i]; }
    }
    const float b2 = by2[0];
    float lam = 0.6f, prevn = 3.4e38f;
    bool frozen = false;

    {   // initial pxp[w] = sum_c wy2[c] * x[c]
        float pxs = 0.f;
        #pragma unroll
        for (int i = 0; i < 16; ++i) pxs = fmaf(wy2r[i], xc[i], pxs);
        pxs += __shfl_xor(pxs, 16, 64);
        pxs += __shfl_xor(pxs, 32, 64);
        if (l == 0) pxp[w] = pxs;
    }
    __syncthreads();

    const f16x8* WA0v = (const f16x8*)WA0q;
    const f16x8* WA1v = (const f16x8*)WA1q;
    const f16x8* WAZv = (const f16x8*)WAZq;
    const f16x8* WZTv = (const f16x8*)WZTq;
    const f16x8* W1Tv = (const f16x8*)W1Tq;
    const f16x8* W0Tv = (const f16x8*)W0Tq;
    const float4* by0v = (const float4*)by0f;
    const float4* by1v = (const float4*)by1f;
    const float4* wz2v = (const float4*)wz2f;
    const _Float16* xrow  = xact  + n4 * 72;    // col-role rows (sample n4)
    const _Float16* h0row = h0act + n4 * 136;
    const _Float16* v1row = v1act + n4 * 136;

    float sig0[2][4];
    f32x4 accg[4];   // W1T~v1 per-sample partial, carried I3 -> I4

    for (int it = 0; it < MAX_IT; ++it) {
        // ======== I1: h0 = softplus(Wy0 x + by0), rows mt=w,w+4 ========
        f16x8 bx0 = *(const f16x8*)(xrow + quad * 8);
        f16x8 bx1 = *(const f16x8*)(xrow + 32 + quad * 8);
        float sp_[2][4];
        #pragma unroll
        for (int mi = 0; mi < 2; ++mi) {
            const int mt = w + 4 * mi;
            f32x4 acc = {0.f, 0.f, 0.f, 0.f};
            acc = MFMA(WA0v[(mt * 2 + 0) * 64 + l], bx0, acc);
            acc = MFMA(WA0v[(mt * 2 + 1) * 64 + l], bx1, acc);
            const float4 bb = by0v[mt * 4 + quad];
            sigsp(acc[0] + bb.x, sig0[mi][0], sp_[mi][0]);
            sigsp(acc[1] + bb.y, sig0[mi][1], sp_[mi][1]);
            sigsp(acc[2] + bb.z, sig0[mi][2], sp_[mi][2]);
            sigsp(acc[3] + bb.w, sig0[mi][3], sp_[mi][3]);
            if (n < 4)
                *(uint2*)&h0act[n4 * 136 + mt * 16 + quad * 4] =
                    make_uint2(pack_h2(sp_[mi][0], sp_[mi][1]),
                               pack_h2(sp_[mi][2], sp_[mi][3]));
        }
        __syncthreads();   // B1

        // ======== I2: preact1 -> sig1,h1 ; head partial ; ~v1 = sig1.wz2 ====
        f16x8 bh0 = *(const f16x8*)(h0row + quad * 8);
        f16x8 bh1 = *(const f16x8*)(h0row + 32 + quad * 8);
        f16x8 bh2 = *(const f16x8*)(h0row + 64 + quad * 8);
        f16x8 bh3 = *(const f16x8*)(h0row + 96 + quad * 8);
        float hsum = 0.0f;
        #pragma unroll
        for (int mi = 0; mi < 2; ++mi) {
            const int mt = w + 4 * mi;
            f32x4 acc = {0.f, 0.f, 0.f, 0.f};
            acc = MFMA(WAZv[(mt * 4 + 0) * 64 + l], bh0, acc);
            acc = MFMA(WAZv[(mt * 4 + 1) * 64 + l], bh1, acc);
            acc = MFMA(WAZv[(mt * 4 + 2) * 64 + l], bh2, acc);
            acc = MFMA(WAZv[(mt * 4 + 3) * 64 + l], bh3, acc);
            acc = MFMA(WA1v[(mt * 2 + 0) * 64 + l], bx0, acc);
            acc = MFMA(WA1v[(mt * 2 + 1) * 64 + l], bx1, acc);
            const float4 bb  = by1v[mt * 4 + quad];
            const float4 wzq = wz2v[mt * 4 + quad];
            float s1, h1;
            sigsp(acc[0] + bb.x, s1, h1); hsum = fmaf(wzq.x, h1, hsum);
            float t0 = s1 * wzq.x;
            sigsp(acc[1] + bb.y, s1, h1); hsum = fmaf(wzq.y, h1, hsum);
            float t1 = s1 * wzq.y;
            sigsp(acc[2] + bb.z, s1, h1); hsum = fmaf(wzq.z, h1, hsum);
            float t2 = s1 * wzq.z;
            sigsp(acc[3] + bb.w, s1, h1); hsum = fmaf(wzq.w, h1, hsum);
            float t3 = s1 * wzq.w;
            if (n < 4)
                *(uint2*)&v1act[n4 * 136 + mt * 16 + quad * 4] =
                    make_uint2(pack_h2(t0, t1), pack_h2(t2, t3));
        }
        hsum += __shfl_xor(hsum, 16, 64);
        hsum += __shfl_xor(hsum, 32, 64);
        if (l < 4) hp[l * 4 + w] = hsum;   // hp[n4][w]
        __syncthreads();   // B2 (hp AND ~v1 ready — sg2 deferred)

        // ======== I3: v0 = sig0.sg2.(Wz1+^T ~v1)  +  accg = W1T ~v1 (sample w)
        float sg2c;   // sigmoid of head for col-role sample n4
        {
            const float4 hv = ((const float4*)hp)[n4];
            sg2c = sigm(hv.x + hv.y + hv.z + hv.w + pxp[n4] + b2);
        }
        f16x8 bt0 = *(const f16x8*)(v1row + quad * 8);
        f16x8 bt1 = *(const f16x8*)(v1row + 32 + quad * 8);
        f16x8 bt2 = *(const f16x8*)(v1row + 64 + quad * 8);
        f16x8 bt3 = *(const f16x8*)(v1row + 96 + quad * 8);
        #pragma unroll
        for (int mi = 0; mi < 2; ++mi) {
            const int mt = w + 4 * mi;
            f32x4 acc = {0.f, 0.f, 0.f, 0.f};
            acc = MFMA(WZTv[(mt * 4 + 0) * 64 + l], bt0, acc);
            acc = MFMA(WZTv[(mt * 4 + 1) * 64 + l], bt1, acc);
            acc = MFMA(WZTv[(mt * 4 + 2) * 64 + l], bt2, acc);
            acc = MFMA(WZTv[(mt * 4 + 3) * 64 + l], bt3, acc);
            const float a0 = sig0[mi][0] * sg2c * acc[0];
            const float a1 = sig0[mi][1] * sg2c * acc[1];
            const float a2 = sig0[mi][2] * sg2c * acc[2];
            const float a3 = sig0[mi][3] * sg2c * acc[3];
            if (n < 4)
                *(uint2*)&v0act[n4 * 136 + mt * 16 + quad * 4] =
                    make_uint2(pack_h2(a0, a1), pack_h2(a2, a3));
        }
        {   // per-sample W1T . ~v1_w  (all 4 M-tiles, sample w)
            const _Float16* vw = v1act + w * 136;
            f16x8 bs0 = *(const f16x8*)(vw + quad * 8);
            f16x8 bs1 = *(const f16x8*)(vw + 32 + quad * 8);
            f16x8 bs2 = *(const f16x8*)(vw + 64 + quad * 8);
            f16x8 bs3 = *(const f16x8*)(vw + 96 + quad * 8);
            #pragma unroll
            for (int mt = 0; mt < 4; ++mt) {
                f32x4 a = {0.f, 0.f, 0.f, 0.f};
                a = MFMA(W1Tv[(mt * 4 + 0) * 64 + l], bs0, a);
                a = MFMA(W1Tv[(mt * 4 + 1) * 64 + l], bs1, a);
                a = MFMA(W1Tv[(mt * 4 + 2) * 64 + l], bs2, a);
                a = MFMA(W1Tv[(mt * 4 + 3) * 64 + l], bs3, a);
                accg[mt] = a;
            }
        }
        __syncthreads();   // B3 (v0 ready)

        // ======== I4: g = x + sg2w.wy2 + sg2w.accg + W0T v0_w ; update ======
        float n2tot = 0.f;
        float resid[16];
        if (!frozen) {
            const _Float16* uw = v0act + w * 136;
            f16x8 bu0 = *(const f16x8*)(uw + quad * 8);
            f16x8 bu1 = *(const f16x8*)(uw + 32 + quad * 8);
            f16x8 bu2 = *(const f16x8*)(uw + 64 + quad * 8);
            f16x8 bu3 = *(const f16x8*)(uw + 96 + quad * 8);
            float sg2w;
            {
                const float4 hv = ((const float4*)hp)[w];
                sg2w = sigm(hv.x + hv.y + hv.z + hv.w + pxp[w] + b2);
            }
            #pragma unroll
            for (int mt = 0; mt < 4; ++mt) {
                f32x4 a = {0.f, 0.f, 0.f, 0.f};
                a = MFMA(W0Tv[(mt * 4 + 0) * 64 + l], bu0, a);
                a = MFMA(W0Tv[(mt * 4 + 1) * 64 + l], bu1, a);
                a = MFMA(W0Tv[(mt * 4 + 2) * 64 + l], bu2, a);
                a = MFMA(W0Tv[(mt * 4 + 3) * 64 + l], bu3, a);
                #pragma unroll
                for (int r = 0; r < 4; ++r) {
                    const int i = mt * 4 + r;
                    const float g = xc[i] + sg2w * wy2r[i]
                                  + sg2w * accg[mt][r] + a[r];
                    resid[i] = zr[i] - g;
                    n2tot = fmaf(resid[i], resid[i], n2tot);
                }
            }
            n2tot += __shfl_xor(n2tot, 16, 64);
            n2tot += __shfl_xor(n2tot, 32, 64);

            if (n2tot < TOLF * TOLF) {
                frozen = true;
            } else {
                // heavy-ball + adaptive lambda (lenient safeguard: HB is
                // naturally non-monotone; restart only on 1.3x growth)
                const float nn = sqrtf(n2tot);
                float beta = 0.35f;
                if (nn > 1.3f * prevn) { lam *= 0.5f; beta = 0.0f; }
                else lam = fminf(lam * 1.05f, 1.0f);
                const float step = fmaxf(lam, 1.0f / (float)(it + 2));
                #pragma unroll
                for (int i = 0; i < 16; ++i) {
                    const float nx = xc[i] + step * resid[i] + beta * (xc[i] - xp[i]);
                    xp[i] = xc[i];
                    xc[i] = nx;
                }
                prevn = nn;
                // writeback x (sample w) + pxp
                if (n == 0) {
                    #pragma unroll
                    for (int mt = 0; mt < 4; ++mt)
                        *(uint2*)&xact[w * 72 + mt * 16 + quad * 4] =
                            make_uint2(pack_h2(xc[mt*4+0], xc[mt*4+1]),
                                       pack_h2(xc[mt*4+2], xc[mt*4+3]));
                }
                float pxs = 0.f;
                #pragma unroll
                for (int i = 0; i < 16; ++i) pxs = fmaf(wy2r[i], xc[i], pxs);
                pxs += __shfl_xor(pxs, 16, 64);
                pxs += __shfl_xor(pxs, 32, 64);
                if (l == 0) pxp[w] = pxs;
            }
        }
        if (l == 0) norms[w] = frozen ? 0.0f : n2tot;
        __syncthreads();   // B4 (x, norms ready)

        const float4 nv = *(const float4*)norms;
        const float T2 = TOLF * TOLF;
        if (nv.x < T2 && nv.y < T2 && nv.z < T2 && nv.w < T2) break;
    }

    // ---- output: out = x + CONVEX*z, sample w, lane comps (n==0 lanes) ----
    if (n == 0) {
        float4* out4 = (float4*)out;
        #pragma unroll
        for (int mt = 0; mt < 4; ++mt) {
            float4 o;
            o.x = xc[mt*4+0] + zr[mt*4+0];
            o.y = xc[mt*4+1] + zr[mt*4+1];
            o.z = xc[mt*4+2] + zr[mt*4+2];
            o.w = xc[mt*4+3] + zr[mt*4+3];
            out4[(blk4 + w) * 16 + mt * 4 + quad] = o;
        }
    }
}

extern "C" void kernel_launch(void* const* d_in, const int* in_sizes, int n_in,
                              void* d_out, int out_size, void* d_ws, size_t ws_size,
                              hipStream_t stream) {
    const float* xin = (const float*)d_in[0];
    const float* Wy0 = (const float*)d_in[1];
    const float* by0 = (const float*)d_in[2];
    const float* Wy1 = (const float*)d_in[3];
    const float* by1 = (const float*)d_in[4];
    const float* Wz1 = (const float*)d_in[5];
    const float* Wy2 = (const float*)d_in[6];
    const float* by2 = (const float*)d_in[7];
    const float* Wz2 = (const float*)d_in[8];
    float* out = (float*)d_out;

    blnn_kernel<<<dim3(NB / 4), dim3(256), 0, stream>>>(
        xin, Wy0, by0, Wy1, by1, Wz1, Wy2, by2, Wz2, out);
}

// Round 13
// 88.294 us; speedup vs baseline: 1.3753x; 1.3753x over previous
//
#include <hip/hip_runtime.h>
#include <math.h>

#define NB 1024   // batch
#define NC 64     // input dim
#define NH 128    // hidden dim
#define MAX_IT 500
#define TOLF 1e-3f

typedef _Float16 f16x8 __attribute__((ext_vector_type(8)));
typedef float    f32x4 __attribute__((ext_vector_type(4)));
typedef _Float16 h2    __attribute__((ext_vector_type(2)));

#define MFMA(a, b, c) __builtin_amdgcn_mfma_f32_16x16x32_f16((a), (b), (c), 0, 0, 0)

__device__ __forceinline__ unsigned pack_h2(float a, float b) {
    union { h2 h; unsigned u; } cv;
    cv.h.x = (_Float16)a; cv.h.y = (_Float16)b; return cv.u;
}
__device__ __forceinline__ float rcp_fast(float x) {
#if __has_builtin(__builtin_amdgcn_rcpf)
    return __builtin_amdgcn_rcpf(x);
#else
    return 1.0f / x;
#endif
}
// sigmoid + softplus sharing one exp
__device__ __forceinline__ void sigsp(float a, float& sig, float& sp) {
    const float e = __expf(-fabsf(a));
    const float r = rcp_fast(1.0f + e);
    sig = (a >= 0.0f) ? r : e * r;
    sp  = fmaxf(a, 0.0f) + __logf(1.0f + e);
}
__device__ __forceinline__ float sigm(float a) {
    const float e = __expf(-fabsf(a));
    const float r = rcp_fast(1.0f + e);
    return (a >= 0.0f) ? r : e * r;
}
__device__ __forceinline__ float clp(float x) { return fmaxf(x, 0.0f); }

// R13 = R9 (proven 27 us kernel) + exactly two surgical deltas:
//  (1) deferred sg2: P2 stores ~v1 = sig1*wz2 (head sigmoid folded in later,
//      all consumers linear) -> barriers 6 -> 5, zero added MFMAs.
//  (2) lambda regrowth (x1.15 on >19% n^2 drop, cap 1) so early halvings
//      don't condemn a sample to crawl; strict halving safeguard + Halpern
//      floor retained. (R12's per-sample adjoint + heavy-ball: reverted.)
__launch_bounds__(256, 1)
__global__ void blnn_kernel(const float* __restrict__ xin,
                            const float* __restrict__ Wy0,
                            const float* __restrict__ by0,
                            const float* __restrict__ Wy1,
                            const float* __restrict__ by1,
                            const float* __restrict__ Wz1,
                            const float* __restrict__ Wy2,
                            const float* __restrict__ by2,
                            const float* __restrict__ Wz2,
                            float* __restrict__ out)
{
    // A-frag weight tiles: [tile][lane] uint4 (8 fp16). tile = mt*KS + ks.
    __shared__ uint4 WA0q[16 * 64];   // Wy0   (M=128,K=64):  mt8 x ks2
    __shared__ uint4 WA1q[16 * 64];   // Wy1
    __shared__ uint4 WAZq[32 * 64];   // Wz1+  (M=128,K=128): mt8 x ks4
    __shared__ uint4 WZTq[32 * 64];   // Wz1+^T
    __shared__ uint4 W1Tq[16 * 64];   // Wy1^T (M=64,K=128):  mt4 x ks4
    __shared__ uint4 W0Tq[16 * 64];   // Wy0^T
    __shared__ __align__(16) _Float16 xact [4 * 72];   // x  per sample
    __shared__ __align__(16) _Float16 h0act[4 * 136];  // h0 per sample
    __shared__ __align__(16) _Float16 v1act[4 * 136];  // ~v1 (no sg2)
    __shared__ __align__(16) _Float16 v0act[4 * 136];
    __shared__ __align__(16) float by0f[128], by1f[128], wz2f[128];
    __shared__ __align__(16) float hp[16], pxp[16], npar[16];   // [n4][w]

    const int tid  = threadIdx.x;
    const int w    = tid >> 6;
    const int l    = tid & 63;
    const int n    = l & 15;          // MFMA col
    const int n4   = n & 3;           // real sample
    const int quad = l >> 4;
    const int blk4 = blockIdx.x * 4;

    // ---- stage weights into A-frag order (identical to R9) ----
    for (int f = tid; f < 16 * 64; f += 256) {        // WA0 / WA1
        const int tile = f >> 6, q = f & 63;
        const int mt = tile >> 1, ks = tile & 1;
        const int row = mt * 16 + (q & 15);
        const int k0  = ks * 32 + ((q >> 4) << 3);
        const float* p0 = Wy0 + row * 64 + k0;
        WA0q[f] = make_uint4(pack_h2(p0[0], p0[1]), pack_h2(p0[2], p0[3]),
                             pack_h2(p0[4], p0[5]), pack_h2(p0[6], p0[7]));
        const float* p1 = Wy1 + row * 64 + k0;
        WA1q[f] = make_uint4(pack_h2(p1[0], p1[1]), pack_h2(p1[2], p1[3]),
                             pack_h2(p1[4], p1[5]), pack_h2(p1[6], p1[7]));
    }
    for (int f = tid; f < 32 * 64; f += 256) {        // WAZ / WZT (clip >= 0)
        const int tile = f >> 6, q = f & 63;
        const int mt = tile >> 2, ks = tile & 3;
        const int row = mt * 16 + (q & 15);
        const int k0  = ks * 32 + ((q >> 4) << 3);
        const float* p = Wz1 + row * 128 + k0;
        WAZq[f] = make_uint4(pack_h2(clp(p[0]), clp(p[1])), pack_h2(clp(p[2]), clp(p[3])),
                             pack_h2(clp(p[4]), clp(p[5])), pack_h2(clp(p[6]), clp(p[7])));
        const float* pt = Wz1 + k0 * 128 + row;       // (Wz1^T)[row][k0+j]
        WZTq[f] = make_uint4(pack_h2(clp(pt[0]),   clp(pt[128])),
                             pack_h2(clp(pt[256]), clp(pt[384])),
                             pack_h2(clp(pt[512]), clp(pt[640])),
                             pack_h2(clp(pt[768]), clp(pt[896])));
    }
    for (int f = tid; f < 16 * 64; f += 256) {        // W1T / W0T
        const int tile = f >> 6, q = f & 63;
        const int mt = tile >> 2, ks = tile & 3;
        const int rowT = mt * 16 + (q & 15);          // c in 0..63
        const int k0   = ks * 32 + ((q >> 4) << 3);   // original row
        const float* p1 = Wy1 + k0 * 64 + rowT;
        W1Tq[f] = make_uint4(pack_h2(p1[0],   p1[64]),  pack_h2(p1[128], p1[192]),
                             pack_h2(p1[256], p1[320]), pack_h2(p1[384], p1[448]));
        const float* p0 = Wy0 + k0 * 64 + rowT;
        W0Tq[f] = make_uint4(pack_h2(p0[0],   p0[64]),  pack_h2(p0[128], p0[192]),
                             pack_h2(p0[256], p0[320]), pack_h2(p0[384], p0[448]));
    }
    if (tid < 128) {
        by0f[tid] = by0[tid];
        by1f[tid] = by1[tid];
        wz2f[tid] = fmaxf(Wz2[tid], 0.0f);
    }
    {   // x0 = z into act layout
        const int nn = tid >> 6, cc = tid & 63;
        xact[nn * 72 + cc] = (_Float16)xin[(blk4 + nn) * 64 + cc];
    }

    // ---- per-lane col-role state: rows c = 16w + quad*4 + r, sample n4 ----
    const float4 z4  = ((const float4*)xin)[(blk4 + n4) * 16 + w * 4 + quad];
    const float4 wy4 = ((const float4*)Wy2)[w * 4 + quad];
    float zr[4]   = {z4.x, z4.y, z4.z, z4.w};
    float wy2r[4] = {wy4.x, wy4.y, wy4.z, wy4.w};
    float xcur[4] = {zr[0], zr[1], zr[2], zr[3]};
    float lamE = 1.0f, prevn2 = 3.4e38f;
    const float b2 = by2[0];

    {   // px = sum_c wy2[c]*x[c] for first iteration
        float pxs = wy2r[0]*xcur[0] + wy2r[1]*xcur[1] + wy2r[2]*xcur[2] + wy2r[3]*xcur[3];
        pxs += __shfl_xor(pxs, 16, 64);
        pxs += __shfl_xor(pxs, 32, 64);
        if (l < 4) pxp[l * 4 + w] = pxs;
    }
    __syncthreads();

    const f16x8* WA0v = (const f16x8*)WA0q;
    const f16x8* WA1v = (const f16x8*)WA1q;
    const f16x8* WAZv = (const f16x8*)WAZq;
    const f16x8* WZTv = (const f16x8*)WZTq;
    const f16x8* W1Tv = (const f16x8*)W1Tq;
    const f16x8* W0Tv = (const f16x8*)W0Tq;
    const float4* by0v = (const float4*)by0f;
    const float4* by1v = (const float4*)by1f;
    const float4* wz2v = (const float4*)wz2f;
    const _Float16* xrow  = xact  + n4 * 72;
    const _Float16* h0row = h0act + n4 * 136;
    const _Float16* v1row = v1act + n4 * 136;
    const _Float16* v0row = v0act + n4 * 136;

    float sig0[2][4];

    for (int it = 0; it < MAX_IT; ++it) {
        // ---- P1: preact0 = Wy0 x + by0 -> h0, sig0 ----
        f16x8 bx0 = *(const f16x8*)(xrow + quad * 8);
        f16x8 bx1 = *(const f16x8*)(xrow + 32 + quad * 8);
        #pragma unroll
        for (int mi = 0; mi < 2; ++mi) {
            const int mt = w + 4 * mi;
            f32x4 acc = {0.f, 0.f, 0.f, 0.f};
            acc = MFMA(WA0v[(mt * 2 + 0) * 64 + l], bx0, acc);
            acc = MFMA(WA0v[(mt * 2 + 1) * 64 + l], bx1, acc);
            const float4 bb = by0v[mt * 4 + quad];
            float sp0, sp1, sp2, sp3;
            sigsp(acc[0] + bb.x, sig0[mi][0], sp0);
            sigsp(acc[1] + bb.y, sig0[mi][1], sp1);
            sigsp(acc[2] + bb.z, sig0[mi][2], sp2);
            sigsp(acc[3] + bb.w, sig0[mi][3], sp3);
            if (n < 4)
                *(uint2*)&h0act[n4 * 136 + mt * 16 + quad * 4] =
                    make_uint2(pack_h2(sp0, sp1), pack_h2(sp2, sp3));
        }
        __syncthreads();   // B1: h0 ready

        // ---- P2: preact1 -> sig1,h1 ; head partial ; ~v1 = sig1*wz2 ----
        f16x8 bh0 = *(const f16x8*)(h0row + quad * 8);
        f16x8 bh1 = *(const f16x8*)(h0row + 32 + quad * 8);
        f16x8 bh2 = *(const f16x8*)(h0row + 64 + quad * 8);
        f16x8 bh3 = *(const f16x8*)(h0row + 96 + quad * 8);
        float hsum = 0.0f;
        #pragma unroll
        for (int mi = 0; mi < 2; ++mi) {
            const int mt = w + 4 * mi;
            f32x4 acc = {0.f, 0.f, 0.f, 0.f};
            acc = MFMA(WAZv[(mt * 4 + 0) * 64 + l], bh0, acc);
            acc = MFMA(WAZv[(mt * 4 + 1) * 64 + l], bh1, acc);
            acc = MFMA(WAZv[(mt * 4 + 2) * 64 + l], bh2, acc);
            acc = MFMA(WAZv[(mt * 4 + 3) * 64 + l], bh3, acc);
            acc = MFMA(WA1v[(mt * 2 + 0) * 64 + l], bx0, acc);
            acc = MFMA(WA1v[(mt * 2 + 1) * 64 + l], bx1, acc);
            const float4 bb  = by1v[mt * 4 + quad];
            const float4 wzq = wz2v[mt * 4 + quad];
            float s1, h1;
            sigsp(acc[0] + bb.x, s1, h1); hsum = fmaf(wzq.x, h1, hsum);
            const float t0 = s1 * wzq.x;
            sigsp(acc[1] + bb.y, s1, h1); hsum = fmaf(wzq.y, h1, hsum);
            const float t1 = s1 * wzq.y;
            sigsp(acc[2] + bb.z, s1, h1); hsum = fmaf(wzq.z, h1, hsum);
            const float t2 = s1 * wzq.z;
            sigsp(acc[3] + bb.w, s1, h1); hsum = fmaf(wzq.w, h1, hsum);
            const float t3 = s1 * wzq.w;
            if (n < 4)
                *(uint2*)&v1act[n4 * 136 + mt * 16 + quad * 4] =
                    make_uint2(pack_h2(t0, t1), pack_h2(t2, t3));
        }
        hsum += __shfl_xor(hsum, 16, 64);
        hsum += __shfl_xor(hsum, 32, 64);
        if (l < 4) hp[l * 4 + w] = hsum;   // hp[n4][w]
        __syncthreads();   // B2: hp AND ~v1 ready (sg2 deferred — saves a barrier)

        // ---- P4: sg2; v0 = sig0*sg2*(Wz1+^T ~v1); accg = W1T^T ~v1 ----
        float sg2c;
        {
            const float4 hv = ((const float4*)hp)[n4];
            const float4 pv = ((const float4*)pxp)[n4];
            sg2c = sigm(hv.x + hv.y + hv.z + hv.w + pv.x + pv.y + pv.z + pv.w + b2);
        }
        f16x8 bv10 = *(const f16x8*)(v1row + quad * 8);
        f16x8 bv11 = *(const f16x8*)(v1row + 32 + quad * 8);
        f16x8 bv12 = *(const f16x8*)(v1row + 64 + quad * 8);
        f16x8 bv13 = *(const f16x8*)(v1row + 96 + quad * 8);
        #pragma unroll
        for (int mi = 0; mi < 2; ++mi) {
            const int mt = w + 4 * mi;
            f32x4 acc = {0.f, 0.f, 0.f, 0.f};
            acc = MFMA(WZTv[(mt * 4 + 0) * 64 + l], bv10, acc);
            acc = MFMA(WZTv[(mt * 4 + 1) * 64 + l], bv11, acc);
            acc = MFMA(WZTv[(mt * 4 + 2) * 64 + l], bv12, acc);
            acc = MFMA(WZTv[(mt * 4 + 3) * 64 + l], bv13, acc);
            const float a0 = sig0[mi][0] * sg2c * acc[0];
            const float a1 = sig0[mi][1] * sg2c * acc[1];
            const float a2 = sig0[mi][2] * sg2c * acc[2];
            const float a3 = sig0[mi][3] * sg2c * acc[3];
            if (n < 4)
                *(uint2*)&v0act[n4 * 136 + mt * 16 + quad * 4] =
                    make_uint2(pack_h2(a0, a1), pack_h2(a2, a3));
        }
        f32x4 accg = {0.f, 0.f, 0.f, 0.f};   // Wy1^T ~v1 (col-role rows)
        accg = MFMA(W1Tv[(w * 4 + 0) * 64 + l], bv10, accg);
        accg = MFMA(W1Tv[(w * 4 + 1) * 64 + l], bv11, accg);
        accg = MFMA(W1Tv[(w * 4 + 2) * 64 + l], bv12, accg);
        accg = MFMA(W1Tv[(w * 4 + 3) * 64 + l], bv13, accg);
        __syncthreads();   // B3: v0 ready

        // ---- P6: g = x + sg2*wy2 + sg2*accg + Wy0^T v0 ; residual norm ----
        f16x8 bv00 = *(const f16x8*)(v0row + quad * 8);
        f16x8 bv01 = *(const f16x8*)(v0row + 32 + quad * 8);
        f16x8 bv02 = *(const f16x8*)(v0row + 64 + quad * 8);
        f16x8 bv03 = *(const f16x8*)(v0row + 96 + quad * 8);
        f32x4 acc0 = {0.f, 0.f, 0.f, 0.f};
        acc0 = MFMA(W0Tv[(w * 4 + 0) * 64 + l], bv00, acc0);
        acc0 = MFMA(W0Tv[(w * 4 + 1) * 64 + l], bv01, acc0);
        acc0 = MFMA(W0Tv[(w * 4 + 2) * 64 + l], bv02, acc0);
        acc0 = MFMA(W0Tv[(w * 4 + 3) * 64 + l], bv03, acc0);
        float resid[4];
        float r2 = 0.0f;
        #pragma unroll
        for (int r = 0; r < 4; ++r) {
            const float g = xcur[r] + sg2c * wy2r[r] + sg2c * accg[r] + acc0[r];
            resid[r] = zr[r] - g;
            r2 = fmaf(resid[r], resid[r], r2);
        }
        r2 += __shfl_xor(r2, 16, 64);
        r2 += __shfl_xor(r2, 32, 64);
        if (l < 4) npar[l * 4 + w] = r2;
        __syncthreads();   // B4: norm partials ready

        const float4 q0 = ((const float4*)npar)[0];
        const float4 q1 = ((const float4*)npar)[1];
        const float4 q2 = ((const float4*)npar)[2];
        const float4 q3 = ((const float4*)npar)[3];
        const float s0 = q0.x + q0.y + q0.z + q0.w;
        const float s1 = q1.x + q1.y + q1.z + q1.w;
        const float s2 = q2.x + q2.y + q2.z + q2.w;
        const float s3 = q3.x + q3.y + q3.z + q3.w;
        const float T2 = TOLF * TOLF;
        if (s0 < T2 && s1 < T2 && s2 < T2 && s3 < T2) break;   // uniform

        const float myn2 = (n4 == 0) ? s0 : (n4 == 1) ? s1 : (n4 == 2) ? s2 : s3;
        if (myn2 >= T2) {                    // adaptive Richardson + regrowth
            if (myn2 > prevn2 * 0.998f)      lamE *= 0.5f;               // safeguard
            else if (myn2 < 0.81f * prevn2)  lamE = fminf(lamE * 1.15f, 1.0f);
            const float step = fmaxf(lamE, 1.0f / (float)(it + 2));
            #pragma unroll
            for (int r = 0; r < 4; ++r) xcur[r] = fmaf(step, resid[r], xcur[r]);
            prevn2 = myn2;
        }
        {   // px partial for next iter + x writeback
            float pxs = wy2r[0]*xcur[0] + wy2r[1]*xcur[1] + wy2r[2]*xcur[2] + wy2r[3]*xcur[3];
            pxs += __shfl_xor(pxs, 16, 64);
            pxs += __shfl_xor(pxs, 32, 64);
            if (l < 4) pxp[l * 4 + w] = pxs;
        }
        if (n < 4)
            *(uint2*)&xact[n4 * 72 + w * 16 + quad * 4] =
                make_uint2(pack_h2(xcur[0], xcur[1]), pack_h2(xcur[2], xcur[3]));
        __syncthreads();   // B5: x ready
    }

    if (n < 4) {
        float4 o;
        o.x = xcur[0] + zr[0]; o.y = xcur[1] + zr[1];
        o.z = xcur[2] + zr[2]; o.w = xcur[3] + zr[3];
        ((float4*)out)[(blk4 + n4) * 16 + w * 4 + quad] = o;   // + CONVEX*z
    }
}

extern "C" void kernel_launch(void* const* d_in, const int* in_sizes, int n_in,
                              void* d_out, int out_size, void* d_ws, size_t ws_size,
                              hipStream_t stream) {
    const float* xin = (const float*)d_in[0];
    const float* Wy0 = (const float*)d_in[1];
    const float* by0 = (const float*)d_in[2];
    const float* Wy1 = (const float*)d_in[3];
    const float* by1 = (const float*)d_in[4];
    const float* Wz1 = (const float*)d_in[5];
    const float* Wy2 = (const float*)d_in[6];
    const float* by2 = (const float*)d_in[7];
    const float* Wz2 = (const float*)d_in[8];
    float* out = (float*)d_out;

    blnn_kernel<<<dim3(NB / 4), dim3(256), 0, stream>>>(
        xin, Wy0, by0, Wy1, by1, Wz1, Wy2, by2, Wz2, out);
}

// Round 14
// 85.435 us; speedup vs baseline: 1.4214x; 1.0335x over previous
//
#include <hip/hip_runtime.h>
#include <math.h>

#define NB 1024   // batch
#define NC 64     // input dim
#define NH 128    // hidden dim
#define MAX_IT 500
#define TOLF 1e-3f

typedef _Float16 f16x8 __attribute__((ext_vector_type(8)));
typedef float    f32x4 __attribute__((ext_vector_type(4)));
typedef _Float16 h2    __attribute__((ext_vector_type(2)));

#define MFMA(a, b, c) __builtin_amdgcn_mfma_f32_16x16x32_f16((a), (b), (c), 0, 0, 0)

__device__ __forceinline__ unsigned pack_h2(float a, float b) {
    union { h2 h; unsigned u; } cv;
    cv.h.x = (_Float16)a; cv.h.y = (_Float16)b; return cv.u;
}
__device__ __forceinline__ float rcp_fast(float x) {
#if __has_builtin(__builtin_amdgcn_rcpf)
    return __builtin_amdgcn_rcpf(x);
#else
    return 1.0f / x;
#endif
}
// sigmoid + softplus sharing one exp
__device__ __forceinline__ void sigsp(float a, float& sig, float& sp) {
    const float e = __expf(-fabsf(a));
    const float r = rcp_fast(1.0f + e);
    sig = (a >= 0.0f) ? r : e * r;
    sp  = fmaxf(a, 0.0f) + __logf(1.0f + e);
}
__device__ __forceinline__ float sigm(float a) {
    const float e = __expf(-fabsf(a));
    const float r = rcp_fast(1.0f + e);
    return (a >= 0.0f) ? r : e * r;
}
__device__ __forceinline__ float clp(float x) { return fmaxf(x, 0.0f); }

// R14: the R9-R13 plateau is a LATENCY wall (1 wave/SIMD, zero TLP; phase
// merging and instr shaving were all flat). Single change: 512-thread blocks
// (8 waves) on the same 4 samples -> 2 waves/SIMD co-scheduling (m114):
// row phases split M over 8 waves (1 m-tile each, half the chain), col phase
// duplicated across wave pairs (w, w+4 compute cm=w&3 identically -- free on
// the latency path). LDS/solver/math identical to R13.
__launch_bounds__(512, 1)
__global__ void blnn_kernel(const float* __restrict__ xin,
                            const float* __restrict__ Wy0,
                            const float* __restrict__ by0,
                            const float* __restrict__ Wy1,
                            const float* __restrict__ by1,
                            const float* __restrict__ Wz1,
                            const float* __restrict__ Wy2,
                            const float* __restrict__ by2,
                            const float* __restrict__ Wz2,
                            float* __restrict__ out)
{
    // A-frag weight tiles: [tile][lane] uint4 (8 fp16). tile = mt*KS + ks.
    __shared__ uint4 WA0q[16 * 64];   // Wy0   (M=128,K=64):  mt8 x ks2
    __shared__ uint4 WA1q[16 * 64];   // Wy1
    __shared__ uint4 WAZq[32 * 64];   // Wz1+  (M=128,K=128): mt8 x ks4
    __shared__ uint4 WZTq[32 * 64];   // Wz1+^T
    __shared__ uint4 W1Tq[16 * 64];   // Wy1^T (M=64,K=128):  mt4 x ks4
    __shared__ uint4 W0Tq[16 * 64];   // Wy0^T
    __shared__ __align__(16) _Float16 xact [4 * 72];   // x  per sample
    __shared__ __align__(16) _Float16 h0act[4 * 136];  // h0 per sample
    __shared__ __align__(16) _Float16 v1act[4 * 136];  // ~v1 (no sg2)
    __shared__ __align__(16) _Float16 v0act[4 * 136];
    __shared__ __align__(16) float by0f[128], by1f[128], wz2f[128];
    __shared__ __align__(16) float hp[32];    // head partials [n4][w0..7]
    __shared__ __align__(16) float pxp[16];   // wy2.x partials [n4][cm]
    __shared__ __align__(16) float npar[16];  // norm^2 partials [n4][cm]

    const int tid  = threadIdx.x;
    const int w    = tid >> 6;        // 0..7
    const int cm   = w & 3;           // col-phase m-tile (pairs duplicate)
    const int l    = tid & 63;
    const int n    = l & 15;          // MFMA col
    const int n4   = n & 3;           // real sample
    const int quad = l >> 4;
    const int blk4 = blockIdx.x * 4;

    // ---- stage weights into A-frag order (R9 layouts, 512-thread stride) ----
    for (int f = tid; f < 16 * 64; f += 512) {        // WA0 / WA1
        const int tile = f >> 6, q = f & 63;
        const int mt = tile >> 1, ks = tile & 1;
        const int row = mt * 16 + (q & 15);
        const int k0  = ks * 32 + ((q >> 4) << 3);
        const float* p0 = Wy0 + row * 64 + k0;
        WA0q[f] = make_uint4(pack_h2(p0[0], p0[1]), pack_h2(p0[2], p0[3]),
                             pack_h2(p0[4], p0[5]), pack_h2(p0[6], p0[7]));
        const float* p1 = Wy1 + row * 64 + k0;
        WA1q[f] = make_uint4(pack_h2(p1[0], p1[1]), pack_h2(p1[2], p1[3]),
                             pack_h2(p1[4], p1[5]), pack_h2(p1[6], p1[7]));
    }
    for (int f = tid; f < 32 * 64; f += 512) {        // WAZ / WZT (clip >= 0)
        const int tile = f >> 6, q = f & 63;
        const int mt = tile >> 2, ks = tile & 3;
        const int row = mt * 16 + (q & 15);
        const int k0  = ks * 32 + ((q >> 4) << 3);
        const float* p = Wz1 + row * 128 + k0;
        WAZq[f] = make_uint4(pack_h2(clp(p[0]), clp(p[1])), pack_h2(clp(p[2]), clp(p[3])),
                             pack_h2(clp(p[4]), clp(p[5])), pack_h2(clp(p[6]), clp(p[7])));
        const float* pt = Wz1 + k0 * 128 + row;       // (Wz1^T)[row][k0+j]
        WZTq[f] = make_uint4(pack_h2(clp(pt[0]),   clp(pt[128])),
                             pack_h2(clp(pt[256]), clp(pt[384])),
                             pack_h2(clp(pt[512]), clp(pt[640])),
                             pack_h2(clp(pt[768]), clp(pt[896])));
    }
    for (int f = tid; f < 16 * 64; f += 512) {        // W1T / W0T
        const int tile = f >> 6, q = f & 63;
        const int mt = tile >> 2, ks = tile & 3;
        const int rowT = mt * 16 + (q & 15);          // c in 0..63
        const int k0   = ks * 32 + ((q >> 4) << 3);   // original row
        const float* p1 = Wy1 + k0 * 64 + rowT;
        W1Tq[f] = make_uint4(pack_h2(p1[0],   p1[64]),  pack_h2(p1[128], p1[192]),
                             pack_h2(p1[256], p1[320]), pack_h2(p1[384], p1[448]));
        const float* p0 = Wy0 + k0 * 64 + rowT;
        W0Tq[f] = make_uint4(pack_h2(p0[0],   p0[64]),  pack_h2(p0[128], p0[192]),
                             pack_h2(p0[256], p0[320]), pack_h2(p0[384], p0[448]));
    }
    if (tid < 128) {
        by0f[tid] = by0[tid];
        by1f[tid] = by1[tid];
        wz2f[tid] = fmaxf(Wz2[tid], 0.0f);
    }
    if (tid < 256) {   // x0 = z into act layout
        const int nn = tid >> 6, cc = tid & 63;
        xact[nn * 72 + cc] = (_Float16)xin[(blk4 + nn) * 64 + cc];
    }

    // ---- col-role state: rows c = cm*16 + quad*4 + r, sample n4 ----
    const float4 z4  = ((const float4*)xin)[(blk4 + n4) * 16 + cm * 4 + quad];
    const float4 wy4 = ((const float4*)Wy2)[cm * 4 + quad];
    float zr[4]   = {z4.x, z4.y, z4.z, z4.w};
    float wy2r[4] = {wy4.x, wy4.y, wy4.z, wy4.w};
    float xcur[4] = {zr[0], zr[1], zr[2], zr[3]};
    float lamE = 1.0f, prevn2 = 3.4e38f;
    const float b2 = by2[0];

    {   // px = sum_c wy2[c]*x[c] for first iteration
        float pxs = wy2r[0]*xcur[0] + wy2r[1]*xcur[1] + wy2r[2]*xcur[2] + wy2r[3]*xcur[3];
        pxs += __shfl_xor(pxs, 16, 64);
        pxs += __shfl_xor(pxs, 32, 64);
        if (w < 4 && l < 4) pxp[l * 4 + w] = pxs;
    }
    __syncthreads();

    const f16x8* WA0v = (const f16x8*)WA0q;
    const f16x8* WA1v = (const f16x8*)WA1q;
    const f16x8* WAZv = (const f16x8*)WAZq;
    const f16x8* WZTv = (const f16x8*)WZTq;
    const f16x8* W1Tv = (const f16x8*)W1Tq;
    const f16x8* W0Tv = (const f16x8*)W0Tq;
    const float4* by0v = (const float4*)by0f;
    const float4* by1v = (const float4*)by1f;
    const float4* wz2v = (const float4*)wz2f;
    const _Float16* xrow  = xact  + n4 * 72;
    const _Float16* h0row = h0act + n4 * 136;
    const _Float16* v1row = v1act + n4 * 136;
    const _Float16* v0row = v0act + n4 * 136;

    float sig0[4];

    for (int it = 0; it < MAX_IT; ++it) {
        // ---- P1: preact0 = Wy0 x + by0 -> h0, sig0 (m-tile w) ----
        f16x8 bx0 = *(const f16x8*)(xrow + quad * 8);
        f16x8 bx1 = *(const f16x8*)(xrow + 32 + quad * 8);
        {
            f32x4 acc = {0.f, 0.f, 0.f, 0.f};
            acc = MFMA(WA0v[(w * 2 + 0) * 64 + l], bx0, acc);
            acc = MFMA(WA0v[(w * 2 + 1) * 64 + l], bx1, acc);
            const float4 bb = by0v[w * 4 + quad];
            float sp0, sp1, sp2, sp3;
            sigsp(acc[0] + bb.x, sig0[0], sp0);
            sigsp(acc[1] + bb.y, sig0[1], sp1);
            sigsp(acc[2] + bb.z, sig0[2], sp2);
            sigsp(acc[3] + bb.w, sig0[3], sp3);
            if (n < 4)
                *(uint2*)&h0act[n4 * 136 + w * 16 + quad * 4] =
                    make_uint2(pack_h2(sp0, sp1), pack_h2(sp2, sp3));
        }
        __syncthreads();   // B1: h0 ready

        // ---- P2: preact1 -> sig1,h1 ; head partial ; ~v1 (m-tile w) ----
        f16x8 bh0 = *(const f16x8*)(h0row + quad * 8);
        f16x8 bh1 = *(const f16x8*)(h0row + 32 + quad * 8);
        f16x8 bh2 = *(const f16x8*)(h0row + 64 + quad * 8);
        f16x8 bh3 = *(const f16x8*)(h0row + 96 + quad * 8);
        float hsum = 0.0f;
        {
            f32x4 acc = {0.f, 0.f, 0.f, 0.f};
            acc = MFMA(WAZv[(w * 4 + 0) * 64 + l], bh0, acc);
            acc = MFMA(WAZv[(w * 4 + 1) * 64 + l], bh1, acc);
            acc = MFMA(WAZv[(w * 4 + 2) * 64 + l], bh2, acc);
            acc = MFMA(WAZv[(w * 4 + 3) * 64 + l], bh3, acc);
            acc = MFMA(WA1v[(w * 2 + 0) * 64 + l], bx0, acc);
            acc = MFMA(WA1v[(w * 2 + 1) * 64 + l], bx1, acc);
            const float4 bb  = by1v[w * 4 + quad];
            const float4 wzq = wz2v[w * 4 + quad];
            float s1, h1;
            sigsp(acc[0] + bb.x, s1, h1); hsum = fmaf(wzq.x, h1, hsum);
            const float t0 = s1 * wzq.x;
            sigsp(acc[1] + bb.y, s1, h1); hsum = fmaf(wzq.y, h1, hsum);
            const float t1 = s1 * wzq.y;
            sigsp(acc[2] + bb.z, s1, h1); hsum = fmaf(wzq.z, h1, hsum);
            const float t2 = s1 * wzq.z;
            sigsp(acc[3] + bb.w, s1, h1); hsum = fmaf(wzq.w, h1, hsum);
            const float t3 = s1 * wzq.w;
            if (n < 4)
                *(uint2*)&v1act[n4 * 136 + w * 16 + quad * 4] =
                    make_uint2(pack_h2(t0, t1), pack_h2(t2, t3));
        }
        hsum += __shfl_xor(hsum, 16, 64);
        hsum += __shfl_xor(hsum, 32, 64);
        if (l < 4) hp[l * 8 + w] = hsum;   // hp[n4][w], 8 m-tiles
        __syncthreads();   // B2: hp AND ~v1 ready (sg2 deferred)

        // ---- P4: sg2; v0 = sig0*sg2*(Wz1+^T ~v1) (m-tile w); accg (cm) ----
        float sg2c;
        {
            const float4 h0v = ((const float4*)hp)[n4 * 2];
            const float4 h1v = ((const float4*)hp)[n4 * 2 + 1];
            const float4 pv  = ((const float4*)pxp)[n4];
            sg2c = sigm(h0v.x + h0v.y + h0v.z + h0v.w +
                        h1v.x + h1v.y + h1v.z + h1v.w +
                        pv.x + pv.y + pv.z + pv.w + b2);
        }
        f16x8 bv10 = *(const f16x8*)(v1row + quad * 8);
        f16x8 bv11 = *(const f16x8*)(v1row + 32 + quad * 8);
        f16x8 bv12 = *(const f16x8*)(v1row + 64 + quad * 8);
        f16x8 bv13 = *(const f16x8*)(v1row + 96 + quad * 8);
        {
            f32x4 acc = {0.f, 0.f, 0.f, 0.f};
            acc = MFMA(WZTv[(w * 4 + 0) * 64 + l], bv10, acc);
            acc = MFMA(WZTv[(w * 4 + 1) * 64 + l], bv11, acc);
            acc = MFMA(WZTv[(w * 4 + 2) * 64 + l], bv12, acc);
            acc = MFMA(WZTv[(w * 4 + 3) * 64 + l], bv13, acc);
            const float a0 = sig0[0] * sg2c * acc[0];
            const float a1 = sig0[1] * sg2c * acc[1];
            const float a2 = sig0[2] * sg2c * acc[2];
            const float a3 = sig0[3] * sg2c * acc[3];
            if (n < 4)
                *(uint2*)&v0act[n4 * 136 + w * 16 + quad * 4] =
                    make_uint2(pack_h2(a0, a1), pack_h2(a2, a3));
        }
        f32x4 accg = {0.f, 0.f, 0.f, 0.f};   // Wy1^T ~v1 (col m-tile cm)
        accg = MFMA(W1Tv[(cm * 4 + 0) * 64 + l], bv10, accg);
        accg = MFMA(W1Tv[(cm * 4 + 1) * 64 + l], bv11, accg);
        accg = MFMA(W1Tv[(cm * 4 + 2) * 64 + l], bv12, accg);
        accg = MFMA(W1Tv[(cm * 4 + 3) * 64 + l], bv13, accg);
        __syncthreads();   // B3: v0 ready

        // ---- P6: g = x + sg2*wy2 + sg2*accg + Wy0^T v0 ; residual norm ----
        f16x8 bv00 = *(const f16x8*)(v0row + quad * 8);
        f16x8 bv01 = *(const f16x8*)(v0row + 32 + quad * 8);
        f16x8 bv02 = *(const f16x8*)(v0row + 64 + quad * 8);
        f16x8 bv03 = *(const f16x8*)(v0row + 96 + quad * 8);
        f32x4 acc0 = {0.f, 0.f, 0.f, 0.f};
        acc0 = MFMA(W0Tv[(cm * 4 + 0) * 64 + l], bv00, acc0);
        acc0 = MFMA(W0Tv[(cm * 4 + 1) * 64 + l], bv01, acc0);
        acc0 = MFMA(W0Tv[(cm * 4 + 2) * 64 + l], bv02, acc0);
        acc0 = MFMA(W0Tv[(cm * 4 + 3) * 64 + l], bv03, acc0);
        float resid[4];
        float r2 = 0.0f;
        #pragma unroll
        for (int r = 0; r < 4; ++r) {
            const float g = xcur[r] + sg2c * wy2r[r] + sg2c * accg[r] + acc0[r];
            resid[r] = zr[r] - g;
            r2 = fmaf(resid[r], resid[r], r2);
        }
        r2 += __shfl_xor(r2, 16, 64);
        r2 += __shfl_xor(r2, 32, 64);
        if (w < 4 && l < 4) npar[l * 4 + w] = r2;   // npar[n4][cm]
        __syncthreads();   // B4: norm partials ready

        const float4 q0 = ((const float4*)npar)[0];
        const float4 q1 = ((const float4*)npar)[1];
        const float4 q2 = ((const float4*)npar)[2];
        const float4 q3 = ((const float4*)npar)[3];
        const float s0 = q0.x + q0.y + q0.z + q0.w;
        const float s1 = q1.x + q1.y + q1.z + q1.w;
        const float s2 = q2.x + q2.y + q2.z + q2.w;
        const float s3 = q3.x + q3.y + q3.z + q3.w;
        const float T2 = TOLF * TOLF;
        if (s0 < T2 && s1 < T2 && s2 < T2 && s3 < T2) break;   // uniform

        const float myn2 = (n4 == 0) ? s0 : (n4 == 1) ? s1 : (n4 == 2) ? s2 : s3;
        if (myn2 >= T2) {                    // adaptive Richardson (R3 solver)
            if (myn2 > prevn2 * 0.998f) lamE *= 0.5f;
            const float step = fmaxf(lamE, 1.0f / (float)(it + 2));
            #pragma unroll
            for (int r = 0; r < 4; ++r) xcur[r] = fmaf(step, resid[r], xcur[r]);
            prevn2 = myn2;
        }
        {   // px partial for next iter + x writeback
            float pxs = wy2r[0]*xcur[0] + wy2r[1]*xcur[1] + wy2r[2]*xcur[2] + wy2r[3]*xcur[3];
            pxs += __shfl_xor(pxs, 16, 64);
            pxs += __shfl_xor(pxs, 32, 64);
            if (w < 4 && l < 4) pxp[l * 4 + w] = pxs;
        }
        if (w < 4 && n < 4)
            *(uint2*)&xact[n4 * 72 + cm * 16 + quad * 4] =
                make_uint2(pack_h2(xcur[0], xcur[1]), pack_h2(xcur[2], xcur[3]));
        __syncthreads();   // B5: x ready
    }

    if (w < 4 && n < 4) {
        float4 o;
        o.x = xcur[0] + zr[0]; o.y = xcur[1] + zr[1];
        o.z = xcur[2] + zr[2]; o.w = xcur[3] + zr[3];
        ((float4*)out)[(blk4 + n4) * 16 + cm * 4 + quad] = o;   // + CONVEX*z
    }
}

extern "C" void kernel_launch(void* const* d_in, const int* in_sizes, int n_in,
                              void* d_out, int out_size, void* d_ws, size_t ws_size,
                              hipStream_t stream) {
    const float* xin = (const float*)d_in[0];
    const float* Wy0 = (const float*)d_in[1];
    const float* by0 = (const float*)d_in[2];
    const float* Wy1 = (const float*)d_in[3];
    const float* by1 = (const float*)d_in[4];
    const float* Wz1 = (const float*)d_in[5];
    const float* Wy2 = (const float*)d_in[6];
    const float* by2 = (const float*)d_in[7];
    const float* Wz2 = (const float*)d_in[8];
    float* out = (float*)d_out;

    blnn_kernel<<<dim3(NB / 4), dim3(512), 0, stream>>>(
        xin, Wy0, by0, Wy1, by1, Wz1, Wy2, by2, Wz2, out);
}